// Round 4
// baseline (361.306 us; speedup 1.0000x reference)
//
#include <hip/hip_runtime.h>
#include <hip/hip_bf16.h>

#define C 128
#define L 16384
#define B 8
#define MID 32
#define NBL (B * L)

typedef unsigned short ushort_t;
typedef __attribute__((ext_vector_type(8))) short s8v;   // 8 bf16
typedef __attribute__((ext_vector_type(4))) float f4v;   // 4 fp32
typedef __attribute__((ext_vector_type(8))) float f8v;   // 8 fp32

__device__ __forceinline__ unsigned short f2bf(float f) {
    union { float f; unsigned int u; } a; a.f = f;
    unsigned int u = a.u;
    return (unsigned short)((u + 0x7fffu + ((u >> 16) & 1u)) >> 16);
}

// value-style helpers: no address-taken locals
__device__ __forceinline__ f8v unp8(s8v v) {
    f8v f;
#pragma unroll
    for (int j = 0; j < 8; j++) f[j] = __uint_as_float(((unsigned int)(unsigned short)v[j]) << 16);
    return f;
}

__device__ __forceinline__ f8v ldf8(const float* p) {
    float4 a = *(const float4*)p;
    float4 b = *(const float4*)(p + 4);
    f8v f;
    f[0] = a.x; f[1] = a.y; f[2] = a.z; f[3] = a.w;
    f[4] = b.x; f[5] = b.y; f[6] = b.z; f[7] = b.w;
    return f;
}

// fragment-order index for staged weights: slot in [0,13), o = out channel row, w = col within slot's 32
__device__ __forceinline__ int widx(int slot, int o, int w) {
    return ((slot * 8 + (o >> 4)) * 64 + (w >> 3) * 16 + (o & 15)) * 8 + (w & 7);
}

// ------------------------------------------------ k_cvt: x fp32 [b][c][l] -> xb bf16 [b][l][c], + gap sums
__global__ __launch_bounds__(256) void k_cvt(const float* __restrict__ x,
                                             ushort_t* __restrict__ xb,
                                             float* __restrict__ gap) {
    __shared__ float xs[64][129];
    const int bid = blockIdx.x;
    const int b = bid >> 8;
    const int l0 = (bid & 255) * 64;
    const int tid = threadIdx.x;
    const int c = tid >> 1, h = tid & 1;
    const float* src = x + ((size_t)(b * C + c)) * L + l0 + h * 32;
    float s = 0.f;
#pragma unroll
    for (int j = 0; j < 8; j++) {
        float4 v = *(const float4*)(src + j * 4);
        s += (v.x + v.y) + (v.z + v.w);
        int lb = h * 32 + j * 4;
        xs[lb + 0][c] = v.x; xs[lb + 1][c] = v.y;
        xs[lb + 2][c] = v.z; xs[lb + 3][c] = v.w;
    }
    s += __shfl_xor(s, 1);
    if (h == 0) atomicAdd(&gap[b * C + c], s);
    __syncthreads();
    const int l = tid & 63, quarter = tid >> 6, cb = quarter * 32;
    union { ushort_t hh[32]; uint4 q[4]; } u;
#pragma unroll
    for (int k = 0; k < 32; k++) u.hh[k] = f2bf(xs[l][cb + k]);
    uint4* dst = (uint4*)(xb + ((size_t)(b * L + l0 + l)) * C + cb);
#pragma unroll
    for (int k = 0; k < 4; k++) dst[k] = u.q[k];
}

// ------------------------------------------------ k_prep_b: gap -> a (mlp1 coefs), pv = p0/p1/p2 per batch
__global__ __launch_bounds__(128) void k_prep_b(const float* __restrict__ gap,
                                                const float* __restrict__ w1,
                                                const float* __restrict__ Wco,
                                                const float* __restrict__ wcd,
                                                const float* __restrict__ Wci,
                                                float* __restrict__ a,
                                                float* __restrict__ pv) {
    int b = blockIdx.x, c = threadIdx.x;
    __shared__ float gl[C];
    __shared__ float red[C];
    __shared__ float gws[C];
    float v = gap[b * C + c] * (1.f / (float)L);
    red[c] = v * v;
    __syncthreads();
    for (int w = 64; w > 0; w >>= 1) {
        if (c < w) red[c] += red[c + w];
        __syncthreads();
    }
    float nrm = fmaxf(sqrtf(red[0]), 1e-12f);
    gl[c] = v / nrm;
    __syncthreads();
    if (c < MID) {
        float s = 0.f;
        for (int k = 0; k < C; k++) s = fmaf(w1[c * C + k], gl[k], s);
        a[b * MID + c] = s;
    }
    {
        float s = 0.f;
        for (int k = 0; k < C; k++) s = fmaf(gl[k], Wco[k * C + c], s);
        gws[c] = s;
    }
    __syncthreads();
    float p0 = 0.f, p1 = 0.f, p2 = 0.f;
    for (int cc = 0; cc < C; cc++) {
        float wv = Wci[cc * C + c];
        float g = gws[cc];
        p0 = fmaf(g * wcd[3 * cc], wv, p0);
        p1 = fmaf(g * wcd[3 * cc + 1], wv, p1);
        p2 = fmaf(g * wcd[3 * cc + 2], wv, p2);
    }
    pv[b * 384 + c] = p0;
    pv[b * 384 + 128 + c] = p1;
    pv[b * 384 + 256 + c] = p2;
}

// ------------------------------------------------ k_prep_w: compose weights, write in MFMA-fragment order
// slots 0-3: A1 = Wct*diag(k1)*Win ; 4-7: AS = Wct*diag(kS)*Win ; 8-11: Wproj ; 12: Ws = Wproj@w2
__global__ __launch_bounds__(128) void k_prep_w(const float* __restrict__ Win,
                                                const float* __restrict__ Wproj,
                                                const float* __restrict__ Wout,
                                                const float* __restrict__ w2,
                                                const float* __restrict__ b2,
                                                const float* __restrict__ wds,
                                                ushort_t* __restrict__ Wf,
                                                float* __restrict__ bp) {
    int o = blockIdx.x, c = threadIdx.x;
    __shared__ float pr[C];
    __shared__ float wct[C];
    pr[c] = Wproj[o * C + c];
    __syncthreads();
    {
        float s = 0.f;
        for (int k = 0; k < C; k++) s = fmaf(pr[k], Wout[k * C + c], s);
        wct[c] = s;
    }
    __syncthreads();
    float a1 = 0.f, as = 0.f;
    for (int cc = 0; cc < C; cc++) {
        float w = wct[cc];
        float win = Win[cc * C + c];
        a1 = fmaf(w * wds[3 * cc + 1], win, a1);
        as = fmaf(w * (0.25f * (wds[3 * cc] + wds[3 * cc + 2])), win, as);
    }
    const int slot = c >> 5, wi = c & 31;
    Wf[widx(slot, o, wi)] = f2bf(a1);
    Wf[widx(4 + slot, o, wi)] = f2bf(as);
    Wf[widx(8 + slot, o, wi)] = f2bf(pr[c]);
    if (c < MID) {
        float s2 = 0.f;
        for (int k = 0; k < C; k++) s2 = fmaf(pr[k], w2[k * MID + c], s2);
        Wf[widx(12, o, c)] = f2bf(s2);
    }
    if (c == 0) {
        float s3 = 0.f;
        for (int k = 0; k < C; k++) s3 = fmaf(pr[k], b2[k], s3);
        bp[o] = s3;
    }
}

// ------------------------------------------------ k_fused: outt[b][l][o] = A1@xC + AS@(4 nbrs) + Wproj@yd + Ws@silu + bp
// grid 1024 = 8 b * 128 y; 1024 threads = 16 waves = 8 l-groups x 2 o-halves.
// Minimal cross-phase liveness: only acc[4] survives between phases.
__global__ __launch_bounds__(1024) __attribute__((amdgpu_waves_per_eu(4, 4)))
void k_fused(const ushort_t* __restrict__ xb,
             const ushort_t* __restrict__ Wf,
             const float* __restrict__ pv,
             const float* __restrict__ a,
             const float* __restrict__ b1,
             const float* __restrict__ pdw,
             const float* __restrict__ bp,
             float* __restrict__ outt) {
    __shared__ ushort_t wlf[53248];           // 106,496 B, fragment-ordered weights
    const int tid = threadIdx.x;
    int bid = blockIdx.x;
    bid = (bid & 7) * 128 + (bid >> 3);       // bijective XCD swizzle: XCD k owns batch k
    const int b = bid >> 7;
    const int y = bid & 127;

    // stage Wf: 6656 uint4 over 1024 threads
#pragma unroll
    for (int i = 0; i < 7; i++) {
        int idx = tid + i * 1024;
        if (idx < 6656) ((uint4*)wlf)[idx] = ((const uint4*)Wf)[idx];
    }

    const int wave = tid >> 6, lane = tid & 63;
    const int half = wave & 1;                // o-half
    const int lg = wave >> 1;                 // l-group within the row
    const int n = lane & 15, q = lane >> 4;
    const int xg = lg * 16 + n;
    const int l = y * 128 + xg;
    const size_t rb = (size_t)b * L;

    const int rL = (l > 0) ? (l - 1) : -1;
    const int rR = (l < L - 1) ? (l + 1) : -1;
    const int rU = (y > 0) ? (l - 128) : ((xg > 0) ? (16256 + xg - 1) : -1);
    const int rD = (y < 127) ? (l + 128) : ((xg < 127) ? (xg + 1) : -1);
    const int sL = (xg > 0) ? (l - 1) : (l + 1);
    const int sR = (xg < 127) ? (l + 1) : (l - 1);
    const int sU = (y > 0) ? (l - 128) : (l + 128);
    const int sD = (y < 127) ? (l + 128) : (l - 128);

    const float dwt4 = pdw[0] * 0.25f;
    const ushort_t* xrow = xb + (rb + l) * C;

    // ---- phase 1: s1 (channel-path scalar) — nothing live after but s1 ----
    const int rlc = (rL >= 0) ? rL : 0;
    const int rrc = (rR >= 0) ? rR : 0;
    float s1 = 0.f;
#pragma unroll
    for (int ks = 0; ks < 4; ks++) {
        const int c0 = ks * 32 + q * 8;
        f8v xc = unp8(*(const s8v*)(xrow + c0));
        f8v xl = unp8(*(const s8v*)(xb + (rb + rlc) * C + c0));
        f8v xr = unp8(*(const s8v*)(xb + (rb + rrc) * C + c0));
        if (rL < 0) {
#pragma unroll
            for (int j = 0; j < 8; j++) xl[j] = 0.f;
        }
        if (rR < 0) {
#pragma unroll
            for (int j = 0; j < 8; j++) xr[j] = 0.f;
        }
        f8v p0 = ldf8(pv + b * 384 + c0);
        f8v p1 = ldf8(pv + b * 384 + 128 + c0);
        f8v p2 = ldf8(pv + b * 384 + 256 + c0);
#pragma unroll
        for (int j = 0; j < 8; j++) {
            s1 = fmaf(p1[j], xc[j], s1);
            s1 = fmaf(p0[j], xl[j], s1);
            s1 = fmaf(p2[j], xr[j], s1);
        }
    }
    s1 += __shfl_xor(s1, 16);
    s1 += __shfl_xor(s1, 32);

    s8v fs;
    {
        f8v av = ldf8(a + b * MID + q * 8);
        f8v bv = ldf8(b1 + q * 8);
#pragma unroll
        for (int j = 0; j < 8; j++) {
            float pre = fmaf(av[j], s1, bv[j]);
            fs[j] = (short)f2bf(pre / (1.f + __expf(-pre)));
        }
    }

    f4v acc[4];
#pragma unroll
    for (int i = 0; i < 4; i++) acc[i] = (f4v){0.f, 0.f, 0.f, 0.f};

    __syncthreads();

#define AF(slot, mtg) (*(const s8v*)(wlf + ((((slot) * 8 + (mtg)) * 64 + lane) * 8)))

    // ---- phase 2: slot 12 (silu) — fs dies here ----
#pragma unroll
    for (int mt = 0; mt < 4; mt++)
        acc[mt] = __builtin_amdgcn_mfma_f32_16x16x32_bf16(AF(12, half * 4 + mt), fs, acc[mt], 0, 0, 0);

    // ---- phase 3: slots 4-7, AS @ zero-padded stencil neighbors (direct load->MFMA) ----
#pragma unroll
    for (int t = 0; t < 4; t++) {
        const int r = (t == 0) ? rL : (t == 1) ? rR : (t == 2) ? rU : rD;
        const int rc = (r >= 0) ? r : 0;
        const ushort_t* prow = xb + (rb + rc) * C + q * 8;
#pragma unroll
        for (int ks = 0; ks < 4; ks++) {
            s8v v = *(const s8v*)(prow + ks * 32);
            if (r < 0) v = (s8v){0, 0, 0, 0, 0, 0, 0, 0};
#pragma unroll
            for (int mt = 0; mt < 4; mt++)
                acc[mt] = __builtin_amdgcn_mfma_f32_16x16x32_bf16(AF(4 + ks, half * 4 + mt), v, acc[mt], 0, 0, 0);
        }
    }

    // ---- phase 4: per-ks A1 @ xC then Wproj @ yd (incremental diff; nothing survives the ks-iter) ----
#pragma unroll
    for (int ks = 0; ks < 4; ks++) {
        const int c0 = ks * 32 + q * 8;
        s8v vc = *(const s8v*)(xrow + c0);
#pragma unroll
        for (int mt = 0; mt < 4; mt++)
            acc[mt] = __builtin_amdgcn_mfma_f32_16x16x32_bf16(AF(ks, half * 4 + mt), vc, acc[mt], 0, 0, 0);
        f8v xc = unp8(vc);
        f8v d8;
        {
            f8v t1 = unp8(*(const s8v*)(xb + (rb + sL) * C + c0));
#pragma unroll
            for (int j = 0; j < 8; j++) d8[j] = fabsf(xc[j] - t1[j]);
        }
        {
            f8v t1 = unp8(*(const s8v*)(xb + (rb + sR) * C + c0));
#pragma unroll
            for (int j = 0; j < 8; j++) d8[j] += fabsf(xc[j] - t1[j]);
        }
        {
            f8v t1 = unp8(*(const s8v*)(xb + (rb + sU) * C + c0));
#pragma unroll
            for (int j = 0; j < 8; j++) d8[j] += fabsf(xc[j] - t1[j]);
        }
        {
            f8v t1 = unp8(*(const s8v*)(xb + (rb + sD) * C + c0));
#pragma unroll
            for (int j = 0; j < 8; j++) d8[j] += fabsf(xc[j] - t1[j]);
        }
        s8v vy;
#pragma unroll
        for (int j = 0; j < 8; j++) vy[j] = (short)f2bf(fmaf(dwt4, d8[j], xc[j]));
#pragma unroll
        for (int mt = 0; mt < 4; mt++)
            acc[mt] = __builtin_amdgcn_mfma_f32_16x16x32_bf16(AF(8 + ks, half * 4 + mt), vy, acc[mt], 0, 0, 0);
    }

#undef AF

    // ---- epilogue: bias + contiguous float4 store to outt [b][l][o] ----
#pragma unroll
    for (int mt = 0; mt < 4; mt++) {
        const int o0 = (half * 4 + mt) * 16 + q * 4;
        float4 bv4 = *(const float4*)(bp + o0);
        float4 r4;
        r4.x = acc[mt][0] + bv4.x;
        r4.y = acc[mt][1] + bv4.y;
        r4.z = acc[mt][2] + bv4.z;
        r4.w = acc[mt][3] + bv4.w;
        *(float4*)(outt + (rb + l) * C + o0) = r4;
    }
}

// ------------------------------------------------ k_bnstats_t: coalesced per-o sums from outt [b][l][o]
__global__ __launch_bounds__(256) void k_bnstats_t(const float* __restrict__ outt,
                                                   float* __restrict__ stats) {
    const int bid = blockIdx.x;
    const int b = bid >> 7;
    const int lt = bid & 127;
    const int t = threadIdx.x;
    const int og = (t & 31) * 4;
    const int lc = t >> 5;                    // 8 l-lanes
    const float* src = outt + ((size_t)(b * L + lt * 128 + lc)) * C + og;
    float s0 = 0.f, s1 = 0.f, s2 = 0.f, s3 = 0.f;
    float q0 = 0.f, q1 = 0.f, q2 = 0.f, q3 = 0.f;
#pragma unroll
    for (int j = 0; j < 16; j++) {
        float4 v = *(const float4*)(src + (size_t)j * 8 * C);
        s0 += v.x; s1 += v.y; s2 += v.z; s3 += v.w;
        q0 += v.x * v.x; q1 += v.y * v.y; q2 += v.z * v.z; q3 += v.w * v.w;
    }
    __shared__ float rs[8][128];
    __shared__ float rq[8][128];
    rs[lc][og + 0] = s0; rs[lc][og + 1] = s1; rs[lc][og + 2] = s2; rs[lc][og + 3] = s3;
    rq[lc][og + 0] = q0; rq[lc][og + 1] = q1; rq[lc][og + 2] = q2; rq[lc][og + 3] = q3;
    __syncthreads();
    if (t < 128) {
        float s = 0.f, qq = 0.f;
#pragma unroll
        for (int k = 0; k < 8; k++) { s += rs[k][t]; qq += rq[k][t]; }
        atomicAdd(&stats[t], s);
        atomicAdd(&stats[C + t], qq);
    }
}

__global__ void k_bnfin(const float* __restrict__ stats, const float* __restrict__ gamma,
                        const float* __restrict__ beta, float* __restrict__ scsh) {
    int o = threadIdx.x;
    float n = (float)NBL;
    float mu = stats[o] / n;
    float var = stats[C + o] / n - mu * mu;
    float sc = gamma[o] * rsqrtf(var + 1e-5f);
    scsh[o] = sc;
    scsh[C + o] = fmaf(-mu, sc, beta[o]);
}

// ------------------------------------------------ k_bnapply_t: outt [b][l][o] -> outp [b][o][l], scaled
__global__ __launch_bounds__(256) void k_bnapply_t(const float* __restrict__ outt,
                                                   const float* __restrict__ scsh,
                                                   float* __restrict__ outp) {
    __shared__ float tl[64][132];
    const int bid = blockIdx.x;
    const int b = bid >> 8;
    const int lt = bid & 255;
    const int t = threadIdx.x;
    {
        const int r = t >> 2, cq = (t & 3) * 32;
        const float* src = outt + ((size_t)(b * L + lt * 64 + r)) * C + cq;
#pragma unroll
        for (int j = 0; j < 8; j++) {
            float4 v = *(const float4*)(src + j * 4);
            tl[r][cq + j * 4 + 0] = v.x;
            tl[r][cq + j * 4 + 1] = v.y;
            tl[r][cq + j * 4 + 2] = v.z;
            tl[r][cq + j * 4 + 3] = v.w;
        }
    }
    __syncthreads();
    {
        const int o = t >> 1, seg = t & 1;
        const float sc = scsh[o], sh = scsh[C + o];
        float* dst = outp + ((size_t)(b * C + o)) * L + lt * 64 + seg * 32;
#pragma unroll
        for (int j = 0; j < 8; j++) {
            float4 v;
            v.x = fmaf(tl[seg * 32 + j * 4 + 0][o], sc, sh);
            v.y = fmaf(tl[seg * 32 + j * 4 + 1][o], sc, sh);
            v.z = fmaf(tl[seg * 32 + j * 4 + 2][o], sc, sh);
            v.w = fmaf(tl[seg * 32 + j * 4 + 3][o], sc, sh);
            *(float4*)(dst + j * 4) = v;
        }
    }
}

// ------------------------------------------------ launch
extern "C" void kernel_launch(void* const* d_in, const int* in_sizes, int n_in,
                              void* d_out, int out_size, void* d_ws, size_t ws_size,
                              hipStream_t stream) {
    const float* x = (const float*)d_in[0];
    const float* Win = (const float*)d_in[1];
    const float* wds = (const float*)d_in[2];
    const float* Wout = (const float*)d_in[3];
    const float* Wci = (const float*)d_in[4];
    const float* wcd = (const float*)d_in[5];
    const float* Wco = (const float*)d_in[6];
    const float* w1 = (const float*)d_in[7];
    const float* b1 = (const float*)d_in[8];
    const float* w2 = (const float*)d_in[9];
    const float* b2 = (const float*)d_in[10];
    const float* pdw = (const float*)d_in[11];
    const float* gamma = (const float*)d_in[12];
    const float* beta = (const float*)d_in[13];
    const float* Wproj = (const float*)d_in[14];

    char* wsb = (char*)d_ws;
    ushort_t* xb = (ushort_t*)wsb;                       // 33,554,432 B
    ushort_t* Wf = (ushort_t*)(wsb + 33554432);          // 106,496 B
    float* outt = (float*)(wsb + 50331648);              // 67,108,864 B  [b][l][o] fp32
    char* S = wsb + 176160768;
    float* gap  = (float*)(S + 0);        // 1024 B
    float* stats= (float*)(S + 4096);     // 1024 B
    float* scsh = (float*)(S + 5120);     // 1024 B
    float* a    = (float*)(S + 6144);     // 1024 B
    float* bp   = (float*)(S + 8192);     // 512 B
    float* pv   = (float*)(S + 12288);    // 12,288 B
    float* outp = (float*)d_out;

    hipMemsetAsync(S, 0, 5120, stream);  // gap + stats
    k_cvt<<<2048, 256, 0, stream>>>(x, xb, gap);
    k_prep_b<<<8, 128, 0, stream>>>(gap, w1, Wco, wcd, Wci, a, pv);
    k_prep_w<<<128, 128, 0, stream>>>(Win, Wproj, Wout, w2, b2, wds, Wf, bp);
    k_fused<<<1024, 1024, 0, stream>>>(xb, Wf, pv, a, b1, pdw, bp, outt);
    k_bnstats_t<<<1024, 256, 0, stream>>>(outt, stats);
    k_bnfin<<<1, 128, 0, stream>>>(stats, gamma, beta, scsh);
    k_bnapply_t<<<2048, 256, 0, stream>>>(outt, scsh, outp);
}

// Round 5
// 291.657 us; speedup vs baseline: 1.2388x; 1.2388x over previous
//
#include <hip/hip_runtime.h>
#include <hip/hip_bf16.h>

#define C 128
#define L 16384
#define B 8
#define MID 32
#define NBL (B * L)

typedef unsigned short ushort_t;
typedef __attribute__((ext_vector_type(8))) short s8v;   // 8 bf16
typedef __attribute__((ext_vector_type(4))) float f4v;   // 4 fp32
typedef __attribute__((ext_vector_type(8))) float f8v;   // 8 fp32

__device__ __forceinline__ unsigned short f2bf(float f) {
    union { float f; unsigned int u; } a; a.f = f;
    unsigned int u = a.u;
    return (unsigned short)((u + 0x7fffu + ((u >> 16) & 1u)) >> 16);
}

// value-style helpers: no address-taken locals
__device__ __forceinline__ f8v unp8(s8v v) {
    f8v f;
#pragma unroll
    for (int j = 0; j < 8; j++) f[j] = __uint_as_float(((unsigned int)(unsigned short)v[j]) << 16);
    return f;
}

__device__ __forceinline__ f8v ldf8(const float* p) {
    float4 a = *(const float4*)p;
    float4 b = *(const float4*)(p + 4);
    f8v f;
    f[0] = a.x; f[1] = a.y; f[2] = a.z; f[3] = a.w;
    f[4] = b.x; f[5] = b.y; f[6] = b.z; f[7] = b.w;
    return f;
}

// fragment-order index for staged weights: slot in [0,13), o = out channel row, w = col within slot's 32
__device__ __forceinline__ int widx(int slot, int o, int w) {
    return ((slot * 8 + (o >> 4)) * 64 + (w >> 3) * 16 + (o & 15)) * 8 + (w & 7);
}

// ------------------------------------------------ k_cvt: x fp32 [b][c][l] -> xb bf16 [b][l][c], + gap sums
__global__ __launch_bounds__(256) void k_cvt(const float* __restrict__ x,
                                             ushort_t* __restrict__ xb,
                                             float* __restrict__ gap) {
    __shared__ float xs[64][129];
    const int bid = blockIdx.x;
    const int b = bid >> 8;
    const int l0 = (bid & 255) * 64;
    const int tid = threadIdx.x;
    const int c = tid >> 1, h = tid & 1;
    const float* src = x + ((size_t)(b * C + c)) * L + l0 + h * 32;
    float s = 0.f;
#pragma unroll
    for (int j = 0; j < 8; j++) {
        float4 v = *(const float4*)(src + j * 4);
        s += (v.x + v.y) + (v.z + v.w);
        int lb = h * 32 + j * 4;
        xs[lb + 0][c] = v.x; xs[lb + 1][c] = v.y;
        xs[lb + 2][c] = v.z; xs[lb + 3][c] = v.w;
    }
    s += __shfl_xor(s, 1);
    if (h == 0) atomicAdd(&gap[b * C + c], s);
    __syncthreads();
    const int l = tid & 63, quarter = tid >> 6, cb = quarter * 32;
    union { ushort_t hh[32]; uint4 q[4]; } u;
#pragma unroll
    for (int k = 0; k < 32; k++) u.hh[k] = f2bf(xs[l][cb + k]);
    uint4* dst = (uint4*)(xb + ((size_t)(b * L + l0 + l)) * C + cb);
#pragma unroll
    for (int k = 0; k < 4; k++) dst[k] = u.q[k];
}

// ------------------------------------------------ k_prep_b: gap -> a (mlp1 coefs), pv = p0/p1/p2 per batch
__global__ __launch_bounds__(128) void k_prep_b(const float* __restrict__ gap,
                                                const float* __restrict__ w1,
                                                const float* __restrict__ Wco,
                                                const float* __restrict__ wcd,
                                                const float* __restrict__ Wci,
                                                float* __restrict__ a,
                                                float* __restrict__ pv) {
    int b = blockIdx.x, c = threadIdx.x;
    __shared__ float gl[C];
    __shared__ float red[C];
    __shared__ float gws[C];
    float v = gap[b * C + c] * (1.f / (float)L);
    red[c] = v * v;
    __syncthreads();
    for (int w = 64; w > 0; w >>= 1) {
        if (c < w) red[c] += red[c + w];
        __syncthreads();
    }
    float nrm = fmaxf(sqrtf(red[0]), 1e-12f);
    gl[c] = v / nrm;
    __syncthreads();
    if (c < MID) {
        float s = 0.f;
        for (int k = 0; k < C; k++) s = fmaf(w1[c * C + k], gl[k], s);
        a[b * MID + c] = s;
    }
    {
        float s = 0.f;
        for (int k = 0; k < C; k++) s = fmaf(gl[k], Wco[k * C + c], s);
        gws[c] = s;
    }
    __syncthreads();
    float p0 = 0.f, p1 = 0.f, p2 = 0.f;
    for (int cc = 0; cc < C; cc++) {
        float wv = Wci[cc * C + c];
        float g = gws[cc];
        p0 = fmaf(g * wcd[3 * cc], wv, p0);
        p1 = fmaf(g * wcd[3 * cc + 1], wv, p1);
        p2 = fmaf(g * wcd[3 * cc + 2], wv, p2);
    }
    pv[b * 384 + c] = p0;
    pv[b * 384 + 128 + c] = p1;
    pv[b * 384 + 256 + c] = p2;
}

// ------------------------------------------------ k_prep_w: compose weights, write in MFMA-fragment order
// slots 0-3: A1 = Wct*diag(k1)*Win ; 4-7: AS = Wct*diag(kS)*Win ; 8-11: Wproj ; 12: Ws = Wproj@w2
__global__ __launch_bounds__(128) void k_prep_w(const float* __restrict__ Win,
                                                const float* __restrict__ Wproj,
                                                const float* __restrict__ Wout,
                                                const float* __restrict__ w2,
                                                const float* __restrict__ b2,
                                                const float* __restrict__ wds,
                                                ushort_t* __restrict__ Wf,
                                                float* __restrict__ bp) {
    int o = blockIdx.x, c = threadIdx.x;
    __shared__ float pr[C];
    __shared__ float wct[C];
    pr[c] = Wproj[o * C + c];
    __syncthreads();
    {
        float s = 0.f;
        for (int k = 0; k < C; k++) s = fmaf(pr[k], Wout[k * C + c], s);
        wct[c] = s;
    }
    __syncthreads();
    float a1 = 0.f, as = 0.f;
    for (int cc = 0; cc < C; cc++) {
        float w = wct[cc];
        float win = Win[cc * C + c];
        a1 = fmaf(w * wds[3 * cc + 1], win, a1);
        as = fmaf(w * (0.25f * (wds[3 * cc] + wds[3 * cc + 2])), win, as);
    }
    const int slot = c >> 5, wi = c & 31;
    Wf[widx(slot, o, wi)] = f2bf(a1);
    Wf[widx(4 + slot, o, wi)] = f2bf(as);
    Wf[widx(8 + slot, o, wi)] = f2bf(pr[c]);
    if (c < MID) {
        float s2 = 0.f;
        for (int k = 0; k < C; k++) s2 = fmaf(pr[k], w2[k * MID + c], s2);
        Wf[widx(12, o, c)] = f2bf(s2);
    }
    if (c == 0) {
        float s3 = 0.f;
        for (int k = 0; k < C; k++) s3 = fmaf(pr[k], b2[k], s3);
        bp[o] = s3;
    }
}

// ------------------------------------------------ k_fused: outp[b][o][l] = A1@xC + AS@(4 nbrs) + Wproj@yd + Ws@silu + bp
// grid 512 = 8 b * 64 y-pairs; 1024 threads = 16 waves, each wave: 16 l, ALL 128 o (acc[8]).
// No generation duplication; yd fragments derived from stencil fragments via boundary selects (0 extra loads).
// BN partial stats folded into epilogue (shfl -> LDS atomics -> 1 global atomic per o per block).
__global__ __launch_bounds__(1024) __attribute__((amdgpu_waves_per_eu(4, 4)))
void k_fused(const ushort_t* __restrict__ xb,
             const ushort_t* __restrict__ Wf,
             const float* __restrict__ pv,
             const float* __restrict__ a,
             const float* __restrict__ b1,
             const float* __restrict__ pdw,
             const float* __restrict__ bp,
             float* __restrict__ outp,
             float* __restrict__ stats) {
    __shared__ ushort_t wlf[53248];           // 106,496 B, fragment-ordered weights
    __shared__ float sdst[C];
    __shared__ float sdsq[C];
    const int tid = threadIdx.x;
    int bid = blockIdx.x;
    bid = (bid & 7) * 64 + (bid >> 3);        // bijective XCD swizzle: XCD k owns batch k
    const int b = bid >> 6;
    const int y0 = (bid & 63) << 1;

    // stage Wf: 6656 uint4 over 1024 threads; zero LDS stats
#pragma unroll
    for (int i = 0; i < 7; i++) {
        int idx = tid + i * 1024;
        if (idx < 6656) ((uint4*)wlf)[idx] = ((const uint4*)Wf)[idx];
    }
    if (tid < C) { sdst[tid] = 0.f; sdsq[tid] = 0.f; }

    const int wave = tid >> 6, lane = tid & 63;
    const int n = lane & 15, q = lane >> 4;
    const int y = y0 + (wave >> 3);
    const int xg = (wave & 7) * 16 + n;
    const int l = y * 128 + xg;
    const size_t rb = (size_t)b * L;

    const int rL = (l > 0) ? (l - 1) : -1;
    const int rR = (l < L - 1) ? (l + 1) : -1;
    const int rU = (y > 0) ? (l - 128) : ((xg > 0) ? (16256 + xg - 1) : -1);
    const int rD = (y < 127) ? (l + 128) : ((xg < 127) ? (xg + 1) : -1);
    const int rlc = (rL >= 0) ? rL : 0;
    const int rrc = (rR >= 0) ? rR : 0;
    const int ruc = (rU >= 0) ? rU : 0;
    const int rdc = (rD >= 0) ? rD : 0;

    const float dwt4 = pdw[0] * 0.25f;
    const ushort_t* xrow = xb + (rb + l) * C;

    f4v acc[8];
#pragma unroll
    for (int i = 0; i < 8; i++) acc[i] = (f4v){0.f, 0.f, 0.f, 0.f};
    float s1 = 0.f;

    __syncthreads();

#define AF(slot, mt) (*(const s8v*)(wlf + ((((slot) * 8 + (mt)) * 64 + lane) * 8)))

#pragma unroll
    for (int ks = 0; ks < 4; ks++) {
        const int c0 = ks * 32 + q * 8;
        // 5 fragment loads (16B each); zero-pad scan-stencil OOB lanes
        s8v vc = *(const s8v*)(xrow + c0);
        s8v vl = *(const s8v*)(xb + (rb + rlc) * C + c0);
        s8v vr = *(const s8v*)(xb + (rb + rrc) * C + c0);
        s8v vu = *(const s8v*)(xb + (rb + ruc) * C + c0);
        s8v vd = *(const s8v*)(xb + (rb + rdc) * C + c0);
        if (rL < 0) vl = (s8v){0, 0, 0, 0, 0, 0, 0, 0};
        if (rR < 0) vr = (s8v){0, 0, 0, 0, 0, 0, 0, 0};
        if (rU < 0) vu = (s8v){0, 0, 0, 0, 0, 0, 0, 0};
        if (rD < 0) vd = (s8v){0, 0, 0, 0, 0, 0, 0, 0};

        // A1 @ xC
#pragma unroll
        for (int mt = 0; mt < 8; mt++)
            acc[mt] = __builtin_amdgcn_mfma_f32_16x16x32_bf16(AF(ks, mt), vc, acc[mt], 0, 0, 0);
        // AS @ 4 neighbors — one weight ds_read feeds 4 MFMAs
#pragma unroll
        for (int mt = 0; mt < 8; mt++) {
            s8v af = AF(4 + ks, mt);
            acc[mt] = __builtin_amdgcn_mfma_f32_16x16x32_bf16(af, vl, acc[mt], 0, 0, 0);
            acc[mt] = __builtin_amdgcn_mfma_f32_16x16x32_bf16(af, vr, acc[mt], 0, 0, 0);
            acc[mt] = __builtin_amdgcn_mfma_f32_16x16x32_bf16(af, vu, acc[mt], 0, 0, 0);
            acc[mt] = __builtin_amdgcn_mfma_f32_16x16x32_bf16(af, vd, acc[mt], 0, 0, 0);
        }

        // s1 (channel-path scalar) — reuses vc/vl/vr
        f8v xc = unp8(vc);
        f8v xl = unp8(vl);
        f8v xr = unp8(vr);
        {
            f8v p0 = ldf8(pv + b * 384 + c0);
            f8v p1 = ldf8(pv + b * 384 + 128 + c0);
            f8v p2 = ldf8(pv + b * 384 + 256 + c0);
#pragma unroll
            for (int j = 0; j < 8; j++) {
                s1 = fmaf(p1[j], xc[j], s1);
                s1 = fmaf(p0[j], xl[j], s1);
                s1 = fmaf(p2[j], xr[j], s1);
            }
        }

        // yd (reflect-pad diff stencil) — boundary rows alias the opposite loaded fragment
        f8v xu = unp8(vu);
        f8v xd = unp8(vd);
        f8v a1 = (xg > 0) ? xl : xr;          // sL
        f8v a2 = (xg < 127) ? xr : xl;        // sR
        f8v a3 = (y > 0) ? xu : xd;           // sU (wave-uniform select)
        f8v a4 = (y < 127) ? xd : xu;         // sD
        s8v vy;
#pragma unroll
        for (int j = 0; j < 8; j++) {
            float d = fabsf(xc[j] - a1[j]) + fabsf(xc[j] - a2[j]) +
                      fabsf(xc[j] - a3[j]) + fabsf(xc[j] - a4[j]);
            vy[j] = (short)f2bf(fmaf(dwt4, d, xc[j]));
        }
#pragma unroll
        for (int mt = 0; mt < 8; mt++)
            acc[mt] = __builtin_amdgcn_mfma_f32_16x16x32_bf16(AF(8 + ks, mt), vy, acc[mt], 0, 0, 0);
    }

    // silu chunk
    s1 += __shfl_xor(s1, 16);
    s1 += __shfl_xor(s1, 32);
    {
        f8v av = ldf8(a + b * MID + q * 8);
        f8v bv = ldf8(b1 + q * 8);
        s8v fs;
#pragma unroll
        for (int j = 0; j < 8; j++) {
            float pre = fmaf(av[j], s1, bv[j]);
            fs[j] = (short)f2bf(pre / (1.f + __expf(-pre)));
        }
#pragma unroll
        for (int mt = 0; mt < 8; mt++)
            acc[mt] = __builtin_amdgcn_mfma_f32_16x16x32_bf16(AF(12, mt), fs, acc[mt], 0, 0, 0);
    }

#undef AF

    // ---- epilogue: bias + store to outp [b][o][l] + BN partial stats ----
#pragma unroll
    for (int mt = 0; mt < 8; mt++) {
        const int o0 = mt * 16 + q * 4;
        float4 bv4 = *(const float4*)(bp + o0);
#pragma unroll
        for (int i = 0; i < 4; i++) {
            float bai = (i == 0) ? bv4.x : (i == 1) ? bv4.y : (i == 2) ? bv4.z : bv4.w;
            float v = acc[mt][i] + bai;
            outp[((size_t)(b * C + o0 + i)) * L + l] = v;
            float s = v, sq = v * v;
            s += __shfl_xor(s, 1); sq += __shfl_xor(sq, 1);
            s += __shfl_xor(s, 2); sq += __shfl_xor(sq, 2);
            s += __shfl_xor(s, 4); sq += __shfl_xor(sq, 4);
            s += __shfl_xor(s, 8); sq += __shfl_xor(sq, 8);
            if (n == 0) {
                atomicAdd(&sdst[o0 + i], s);
                atomicAdd(&sdsq[o0 + i], sq);
            }
        }
    }
    __syncthreads();
    if (tid < C) {
        atomicAdd(&stats[tid], sdst[tid]);
        atomicAdd(&stats[C + tid], sdsq[tid]);
    }
}

__global__ void k_bnfin(const float* __restrict__ stats, const float* __restrict__ gamma,
                        const float* __restrict__ beta, float* __restrict__ scsh) {
    int o = threadIdx.x;
    float n = (float)NBL;
    float mu = stats[o] / n;
    float var = stats[C + o] / n - mu * mu;
    float sc = gamma[o] * rsqrtf(var + 1e-5f);
    scsh[o] = sc;
    scsh[C + o] = fmaf(-mu, sc, beta[o]);
}

__global__ __launch_bounds__(256) void k_bnapply(float* __restrict__ outp,
                                                 const float* __restrict__ scsh) {
    int bo = blockIdx.x;
    int o = bo & (C - 1);
    float sc = scsh[o], sh = scsh[C + o];
    float4* p = (float4*)(outp + (size_t)bo * L);
    for (int i = threadIdx.x; i < L / 4; i += 256) {
        float4 v = p[i];
        v.x = fmaf(v.x, sc, sh);
        v.y = fmaf(v.y, sc, sh);
        v.z = fmaf(v.z, sc, sh);
        v.w = fmaf(v.w, sc, sh);
        p[i] = v;
    }
}

// ------------------------------------------------ launch
extern "C" void kernel_launch(void* const* d_in, const int* in_sizes, int n_in,
                              void* d_out, int out_size, void* d_ws, size_t ws_size,
                              hipStream_t stream) {
    const float* x = (const float*)d_in[0];
    const float* Win = (const float*)d_in[1];
    const float* wds = (const float*)d_in[2];
    const float* Wout = (const float*)d_in[3];
    const float* Wci = (const float*)d_in[4];
    const float* wcd = (const float*)d_in[5];
    const float* Wco = (const float*)d_in[6];
    const float* w1 = (const float*)d_in[7];
    const float* b1 = (const float*)d_in[8];
    const float* w2 = (const float*)d_in[9];
    const float* b2 = (const float*)d_in[10];
    const float* pdw = (const float*)d_in[11];
    const float* gamma = (const float*)d_in[12];
    const float* beta = (const float*)d_in[13];
    const float* Wproj = (const float*)d_in[14];

    char* wsb = (char*)d_ws;
    ushort_t* xb = (ushort_t*)wsb;                       // 33,554,432 B
    ushort_t* Wf = (ushort_t*)(wsb + 33554432);          // 106,496 B
    char* S = wsb + 176160768;
    float* gap  = (float*)(S + 0);        // 1024 B
    float* stats= (float*)(S + 4096);     // 1024 B
    float* scsh = (float*)(S + 5120);     // 1024 B
    float* a    = (float*)(S + 6144);     // 1024 B
    float* bp   = (float*)(S + 8192);     // 512 B
    float* pv   = (float*)(S + 12288);    // 12,288 B
    float* outp = (float*)d_out;

    hipMemsetAsync(S, 0, 5120, stream);  // gap + stats
    k_cvt<<<2048, 256, 0, stream>>>(x, xb, gap);
    k_prep_b<<<8, 128, 0, stream>>>(gap, w1, Wco, wcd, Wci, a, pv);
    k_prep_w<<<128, 128, 0, stream>>>(Win, Wproj, Wout, w2, b2, wds, Wf, bp);
    k_fused<<<512, 1024, 0, stream>>>(xb, Wf, pv, a, b1, pdw, bp, outp, stats);
    k_bnfin<<<1, 128, 0, stream>>>(stats, gamma, beta, scsh);
    k_bnapply<<<1024, 256, 0, stream>>>(outp, scsh);
}

// Round 6
// 279.199 us; speedup vs baseline: 1.2941x; 1.0446x over previous
//
#include <hip/hip_runtime.h>
#include <hip/hip_bf16.h>

#define C 128
#define L 16384
#define B 8
#define MID 32
#define NBL (B * L)

typedef unsigned short ushort_t;
typedef __attribute__((ext_vector_type(8))) short s8v;   // 8 bf16
typedef __attribute__((ext_vector_type(4))) float f4v;   // 4 fp32
typedef __attribute__((ext_vector_type(8))) float f8v;   // 8 fp32

__device__ __forceinline__ unsigned short f2bf(float f) {
    union { float f; unsigned int u; } a; a.f = f;
    unsigned int u = a.u;
    return (unsigned short)((u + 0x7fffu + ((u >> 16) & 1u)) >> 16);
}

// value-style helpers: no address-taken locals
__device__ __forceinline__ f8v unp8(s8v v) {
    f8v f;
#pragma unroll
    for (int j = 0; j < 8; j++) f[j] = __uint_as_float(((unsigned int)(unsigned short)v[j]) << 16);
    return f;
}

__device__ __forceinline__ f8v ldf8(const float* p) {
    float4 a = *(const float4*)p;
    float4 b = *(const float4*)(p + 4);
    f8v f;
    f[0] = a.x; f[1] = a.y; f[2] = a.z; f[3] = a.w;
    f[4] = b.x; f[5] = b.y; f[6] = b.z; f[7] = b.w;
    return f;
}

// fragment-order index for staged weights: slot in [0,13), o = out channel row, w = col within slot's 32
__device__ __forceinline__ int widx(int slot, int o, int w) {
    return ((slot * 8 + (o >> 4)) * 64 + (w >> 3) * 16 + (o & 15)) * 8 + (w & 7);
}

// ------------------------------------------------ k_cvt: x fp32 [b][c][l] -> xb bf16 [b][l][c], + gap sums
__global__ __launch_bounds__(256) void k_cvt(const float* __restrict__ x,
                                             ushort_t* __restrict__ xb,
                                             float* __restrict__ gap) {
    __shared__ float xs[64][129];
    const int bid = blockIdx.x;
    const int b = bid >> 8;
    const int l0 = (bid & 255) * 64;
    const int tid = threadIdx.x;
    const int c = tid >> 1, h = tid & 1;
    const float* src = x + ((size_t)(b * C + c)) * L + l0 + h * 32;
    float s = 0.f;
#pragma unroll
    for (int j = 0; j < 8; j++) {
        float4 v = *(const float4*)(src + j * 4);
        s += (v.x + v.y) + (v.z + v.w);
        int lb = h * 32 + j * 4;
        xs[lb + 0][c] = v.x; xs[lb + 1][c] = v.y;
        xs[lb + 2][c] = v.z; xs[lb + 3][c] = v.w;
    }
    s += __shfl_xor(s, 1);
    if (h == 0) atomicAdd(&gap[b * C + c], s);
    __syncthreads();
    const int l = tid & 63, quarter = tid >> 6, cb = quarter * 32;
    union { ushort_t hh[32]; uint4 q[4]; } u;
#pragma unroll
    for (int k = 0; k < 32; k++) u.hh[k] = f2bf(xs[l][cb + k]);
    uint4* dst = (uint4*)(xb + ((size_t)(b * L + l0 + l)) * C + cb);
#pragma unroll
    for (int k = 0; k < 4; k++) dst[k] = u.q[k];
}

// ------------------------------------------------ k_prep: merged weight-compose (bid<128) + per-batch gap work (bid>=128)
__global__ __launch_bounds__(128) void k_prep(const float* __restrict__ Win,
                                              const float* __restrict__ Wproj,
                                              const float* __restrict__ Wout,
                                              const float* __restrict__ w2,
                                              const float* __restrict__ b2,
                                              const float* __restrict__ wds,
                                              const float* __restrict__ gap,
                                              const float* __restrict__ w1,
                                              const float* __restrict__ Wco,
                                              const float* __restrict__ wcd,
                                              const float* __restrict__ Wci,
                                              ushort_t* __restrict__ Wf,
                                              float* __restrict__ bp,
                                              float* __restrict__ a,
                                              float* __restrict__ pv) {
    const int bid = blockIdx.x;
    const int c = threadIdx.x;
    if (bid < 128) {
        // ---- weight composition for output row o = bid ----
        const int o = bid;
        __shared__ float pr[C];
        __shared__ float wct[C];
        pr[c] = Wproj[o * C + c];
        __syncthreads();
        {
            float s = 0.f;
            for (int k = 0; k < C; k++) s = fmaf(pr[k], Wout[k * C + c], s);
            wct[c] = s;
        }
        __syncthreads();
        float a1 = 0.f, as = 0.f;
        for (int cc = 0; cc < C; cc++) {
            float w = wct[cc];
            float win = Win[cc * C + c];
            a1 = fmaf(w * wds[3 * cc + 1], win, a1);
            as = fmaf(w * (0.25f * (wds[3 * cc] + wds[3 * cc + 2])), win, as);
        }
        const int slot = c >> 5, wi = c & 31;
        Wf[widx(slot, o, wi)] = f2bf(a1);
        Wf[widx(4 + slot, o, wi)] = f2bf(as);
        Wf[widx(8 + slot, o, wi)] = f2bf(pr[c]);
        if (c < MID) {
            float s2 = 0.f;
            for (int k = 0; k < C; k++) s2 = fmaf(pr[k], w2[k * MID + c], s2);
            Wf[widx(12, o, c)] = f2bf(s2);
        }
        if (c == 0) {
            float s3 = 0.f;
            for (int k = 0; k < C; k++) s3 = fmaf(pr[k], b2[k], s3);
            bp[o] = s3;
        }
    } else {
        // ---- per-batch gap normalize -> a (mlp1 coefs), pv (channel-path taps) ----
        const int b = bid - 128;
        __shared__ float gl[C];
        __shared__ float red[C];
        __shared__ float gws[C];
        float v = gap[b * C + c] * (1.f / (float)L);
        red[c] = v * v;
        __syncthreads();
        for (int w = 64; w > 0; w >>= 1) {
            if (c < w) red[c] += red[c + w];
            __syncthreads();
        }
        float nrm = fmaxf(sqrtf(red[0]), 1e-12f);
        gl[c] = v / nrm;
        __syncthreads();
        if (c < MID) {
            float s = 0.f;
            for (int k = 0; k < C; k++) s = fmaf(w1[c * C + k], gl[k], s);
            a[b * MID + c] = s;
        }
        {
            float s = 0.f;
            for (int k = 0; k < C; k++) s = fmaf(gl[k], Wco[k * C + c], s);
            gws[c] = s;
        }
        __syncthreads();
        float p0 = 0.f, p1 = 0.f, p2 = 0.f;
        for (int cc = 0; cc < C; cc++) {
            float wv = Wci[cc * C + c];
            float g = gws[cc];
            p0 = fmaf(g * wcd[3 * cc], wv, p0);
            p1 = fmaf(g * wcd[3 * cc + 1], wv, p1);
            p2 = fmaf(g * wcd[3 * cc + 2], wv, p2);
        }
        pv[b * 384 + c] = p0;
        pv[b * 384 + 128 + c] = p1;
        pv[b * 384 + 256 + c] = p2;
    }
}

// ------------------------------------------------ k_fused: outp[b][o][l] = A1@xC + AS@(4 nbrs) + Wproj@yd + Ws@silu + bp
// Persistent: grid = 256 (1 block/CU), block owns batch (bid&7) row-group (bid>>3)*4..+3, loops 2 iters of 2 rows.
// Weights + pv staged ONCE; no barriers inside the iter loop. Phased per iter to keep arch-VGPR live set small.
__global__ __launch_bounds__(1024) __attribute__((amdgpu_waves_per_eu(4, 4)))
void k_fused(const ushort_t* __restrict__ xb,
             const ushort_t* __restrict__ Wf,
             const float* __restrict__ pv,
             const float* __restrict__ a,
             const float* __restrict__ b1,
             const float* __restrict__ pdw,
             const float* __restrict__ bp,
             float* __restrict__ outp,
             float* __restrict__ stats) {
    __shared__ ushort_t wlf[53248];           // 106,496 B, fragment-ordered weights
    __shared__ float spv[384];
    __shared__ float sdst[C];
    __shared__ float sdsq[C];
    const int tid = threadIdx.x;
    const int bid = blockIdx.x;
    const int b = bid & 7;                    // XCD k owns batch k (round-robin dispatch)
    const int rg = bid >> 3;                  // 0..31 row-group (4 rows)

    // stage Wf: 6656 uint4 over 1024 threads; pv slice; zero LDS stats
#pragma unroll
    for (int i = 0; i < 7; i++) {
        int idx = tid + i * 1024;
        if (idx < 6656) ((uint4*)wlf)[idx] = ((const uint4*)Wf)[idx];
    }
    if (tid < 384) spv[tid] = pv[b * 384 + tid];
    if (tid < C) { sdst[tid] = 0.f; sdsq[tid] = 0.f; }

    const int wave = tid >> 6, lane = tid & 63;
    const int n = lane & 15, q = lane >> 4;
    const int xg = (wave & 7) * 16 + n;
    const float dwt4 = pdw[0] * 0.25f;
    const size_t rb = (size_t)b * L;

    __syncthreads();

#define AF(slot, mt) (*(const s8v*)(wlf + ((((slot) * 8 + (mt)) * 64 + lane) * 8)))

#pragma unroll 1
    for (int iter = 0; iter < 2; iter++) {
        const int y = rg * 4 + iter * 2 + (wave >> 3);
        const int l = y * 128 + xg;

        const int rL = (l > 0) ? (l - 1) : -1;
        const int rR = (l < L - 1) ? (l + 1) : -1;
        const int rU = (y > 0) ? (l - 128) : ((xg > 0) ? (16256 + xg - 1) : -1);
        const int rD = (y < 127) ? (l + 128) : ((xg < 127) ? (xg + 1) : -1);
        const ushort_t* xrow = xb + (rb + l) * C;
        const ushort_t* prL = xb + (rb + ((rL >= 0) ? rL : 0)) * C;
        const ushort_t* prR = xb + (rb + ((rR >= 0) ? rR : 0)) * C;
        const ushort_t* prU = xb + (rb + ((rU >= 0) ? rU : 0)) * C;
        const ushort_t* prD = xb + (rb + ((rD >= 0) ? rD : 0)) * C;

        // ---- phase 1: s1 — one tap at a time (minimal liveness) ----
        float s1 = 0.f;
#pragma unroll
        for (int ks = 0; ks < 4; ks++) {
            const int c0 = ks * 32 + q * 8;
            {
                f8v xv = unp8(*(const s8v*)(xrow + c0));
                f8v p = ldf8(spv + 128 + c0);
#pragma unroll
                for (int j = 0; j < 8; j++) s1 = fmaf(p[j], xv[j], s1);
            }
            {
                f8v xv = unp8(*(const s8v*)(prL + c0));
                if (rL < 0) {
#pragma unroll
                    for (int j = 0; j < 8; j++) xv[j] = 0.f;
                }
                f8v p = ldf8(spv + c0);
#pragma unroll
                for (int j = 0; j < 8; j++) s1 = fmaf(p[j], xv[j], s1);
            }
            {
                f8v xv = unp8(*(const s8v*)(prR + c0));
                if (rR < 0) {
#pragma unroll
                    for (int j = 0; j < 8; j++) xv[j] = 0.f;
                }
                f8v p = ldf8(spv + 256 + c0);
#pragma unroll
                for (int j = 0; j < 8; j++) s1 = fmaf(p[j], xv[j], s1);
            }
        }
        s1 += __shfl_xor(s1, 16);
        s1 += __shfl_xor(s1, 32);

        f4v acc[8];
#pragma unroll
        for (int i = 0; i < 8; i++) acc[i] = (f4v){0.f, 0.f, 0.f, 0.f};

        // ---- phase 2: silu chunk, fs dies immediately ----
        {
            f8v av = ldf8(a + b * MID + q * 8);
            f8v bv = ldf8(b1 + q * 8);
            s8v fs;
#pragma unroll
            for (int j = 0; j < 8; j++) {
                float pre = fmaf(av[j], s1, bv[j]);
                fs[j] = (short)f2bf(pre / (1.f + __expf(-pre)));
            }
#pragma unroll
            for (int mt = 0; mt < 8; mt++)
                acc[mt] = __builtin_amdgcn_mfma_f32_16x16x32_bf16(AF(12, mt), fs, acc[mt], 0, 0, 0);
        }

        // ---- phase 3: per-ks MFMA + incremental yd ----
#pragma unroll
        for (int ks = 0; ks < 4; ks++) {
            const int c0 = ks * 32 + q * 8;
            s8v vc = *(const s8v*)(xrow + c0);
            s8v vl = *(const s8v*)(prL + c0);
            s8v vr = *(const s8v*)(prR + c0);
            s8v vu = *(const s8v*)(prU + c0);
            s8v vd = *(const s8v*)(prD + c0);
            if (rL < 0) vl = (s8v){0, 0, 0, 0, 0, 0, 0, 0};
            if (rR < 0) vr = (s8v){0, 0, 0, 0, 0, 0, 0, 0};
            if (rU < 0) vu = (s8v){0, 0, 0, 0, 0, 0, 0, 0};
            if (rD < 0) vd = (s8v){0, 0, 0, 0, 0, 0, 0, 0};

            // A1 @ xC
#pragma unroll
            for (int mt = 0; mt < 8; mt++)
                acc[mt] = __builtin_amdgcn_mfma_f32_16x16x32_bf16(AF(ks, mt), vc, acc[mt], 0, 0, 0);
            // AS @ 4 neighbors — one weight ds_read feeds 4 MFMAs
#pragma unroll
            for (int mt = 0; mt < 8; mt++) {
                s8v af = AF(4 + ks, mt);
                acc[mt] = __builtin_amdgcn_mfma_f32_16x16x32_bf16(af, vl, acc[mt], 0, 0, 0);
                acc[mt] = __builtin_amdgcn_mfma_f32_16x16x32_bf16(af, vr, acc[mt], 0, 0, 0);
                acc[mt] = __builtin_amdgcn_mfma_f32_16x16x32_bf16(af, vu, acc[mt], 0, 0, 0);
                acc[mt] = __builtin_amdgcn_mfma_f32_16x16x32_bf16(af, vd, acc[mt], 0, 0, 0);
            }

            // yd incrementally (reflect-pad aliases the opposite loaded fragment; selects are cheap)
            f8v xc = unp8(vc);
            f8v d8;
            {
                f8v t = unp8((xg > 0) ? vl : vr);
#pragma unroll
                for (int j = 0; j < 8; j++) d8[j] = fabsf(xc[j] - t[j]);
            }
            {
                f8v t = unp8((xg < 127) ? vr : vl);
#pragma unroll
                for (int j = 0; j < 8; j++) d8[j] += fabsf(xc[j] - t[j]);
            }
            {
                f8v t = unp8((y > 0) ? vu : vd);
#pragma unroll
                for (int j = 0; j < 8; j++) d8[j] += fabsf(xc[j] - t[j]);
            }
            {
                f8v t = unp8((y < 127) ? vd : vu);
#pragma unroll
                for (int j = 0; j < 8; j++) d8[j] += fabsf(xc[j] - t[j]);
            }
            s8v vy;
#pragma unroll
            for (int j = 0; j < 8; j++) vy[j] = (short)f2bf(fmaf(dwt4, d8[j], xc[j]));
#pragma unroll
            for (int mt = 0; mt < 8; mt++)
                acc[mt] = __builtin_amdgcn_mfma_f32_16x16x32_bf16(AF(8 + ks, mt), vy, acc[mt], 0, 0, 0);
        }

        // ---- epilogue: bias + store to outp [b][o][l] + BN partial stats ----
#pragma unroll
        for (int mt = 0; mt < 8; mt++) {
            const int o0 = mt * 16 + q * 4;
            float4 bv4 = *(const float4*)(bp + o0);
#pragma unroll
            for (int i = 0; i < 4; i++) {
                float bai = (i == 0) ? bv4.x : (i == 1) ? bv4.y : (i == 2) ? bv4.z : bv4.w;
                float v = acc[mt][i] + bai;
                outp[((size_t)(b * C + o0 + i)) * L + l] = v;
                float s = v, sq = v * v;
                s += __shfl_xor(s, 1); sq += __shfl_xor(sq, 1);
                s += __shfl_xor(s, 2); sq += __shfl_xor(sq, 2);
                s += __shfl_xor(s, 4); sq += __shfl_xor(sq, 4);
                s += __shfl_xor(s, 8); sq += __shfl_xor(sq, 8);
                if (n == 0) {
                    atomicAdd(&sdst[o0 + i], s);
                    atomicAdd(&sdsq[o0 + i], sq);
                }
            }
        }
    }

#undef AF

    __syncthreads();
    if (tid < C) {
        atomicAdd(&stats[tid], sdst[tid]);
        atomicAdd(&stats[C + tid], sdsq[tid]);
    }
}

// ------------------------------------------------ k_bnapply: inline finalize (per-block scalar) + scale/shift
__global__ __launch_bounds__(256) void k_bnapply(float* __restrict__ outp,
                                                 const float* __restrict__ stats,
                                                 const float* __restrict__ gamma,
                                                 const float* __restrict__ beta) {
    int bo = blockIdx.x;
    int o = bo & (C - 1);
    float nn = (float)NBL;
    float mu = stats[o] / nn;
    float var = stats[C + o] / nn - mu * mu;
    float sc = gamma[o] * rsqrtf(var + 1e-5f);
    float sh = fmaf(-mu, sc, beta[o]);
    float4* p = (float4*)(outp + (size_t)bo * L);
    for (int i = threadIdx.x; i < L / 4; i += 256) {
        float4 v = p[i];
        v.x = fmaf(v.x, sc, sh);
        v.y = fmaf(v.y, sc, sh);
        v.z = fmaf(v.z, sc, sh);
        v.w = fmaf(v.w, sc, sh);
        p[i] = v;
    }
}

// ------------------------------------------------ launch
extern "C" void kernel_launch(void* const* d_in, const int* in_sizes, int n_in,
                              void* d_out, int out_size, void* d_ws, size_t ws_size,
                              hipStream_t stream) {
    const float* x = (const float*)d_in[0];
    const float* Win = (const float*)d_in[1];
    const float* wds = (const float*)d_in[2];
    const float* Wout = (const float*)d_in[3];
    const float* Wci = (const float*)d_in[4];
    const float* wcd = (const float*)d_in[5];
    const float* Wco = (const float*)d_in[6];
    const float* w1 = (const float*)d_in[7];
    const float* b1 = (const float*)d_in[8];
    const float* w2 = (const float*)d_in[9];
    const float* b2 = (const float*)d_in[10];
    const float* pdw = (const float*)d_in[11];
    const float* gamma = (const float*)d_in[12];
    const float* beta = (const float*)d_in[13];
    const float* Wproj = (const float*)d_in[14];

    char* wsb = (char*)d_ws;
    ushort_t* xb = (ushort_t*)wsb;                       // 33,554,432 B
    ushort_t* Wf = (ushort_t*)(wsb + 33554432);          // 106,496 B
    char* S = wsb + 176160768;
    float* gap  = (float*)(S + 0);        // 1024 B
    float* stats= (float*)(S + 4096);     // 1024 B
    float* a    = (float*)(S + 6144);     // 1024 B
    float* bp   = (float*)(S + 8192);     // 512 B
    float* pv   = (float*)(S + 12288);    // 12,288 B
    float* outp = (float*)d_out;

    hipMemsetAsync(S, 0, 5120, stream);  // gap + stats
    k_cvt<<<2048, 256, 0, stream>>>(x, xb, gap);
    k_prep<<<136, 128, 0, stream>>>(Win, Wproj, Wout, w2, b2, wds,
                                    gap, w1, Wco, wcd, Wci, Wf, bp, a, pv);
    k_fused<<<256, 1024, 0, stream>>>(xb, Wf, pv, a, b1, pdw, bp, outp, stats);
    k_bnapply<<<1024, 256, 0, stream>>>(outp, stats, gamma, beta);
}